// Round 1
// baseline (267.568 us; speedup 1.0000x reference)
//
#include <hip/hip_runtime.h>

// B = 4,000,000 rows. One row per thread, 256 rows per block.
// Stage global<->LDS so every global memory instruction is unit-stride 16B.
//
// Cache policy (this round's change):
//   - input loads: REGULAR (no nt). Input is 112 MB, re-read every timed
//     iteration -> fits and stays resident in the 256 MB Infinity Cache.
//     nt loads were forcing HBM re-fetch each iteration.
//   - output stores: NONTEMPORAL. Write-once stream; no-allocate keeps the
//     192 MB output from evicting the input's L3 residency.
//
// LDS layout:
//   s_in : 1792 floats (256 rows * 7), linear — written by coalesced 16B
//          loads, read per-thread at stride 7 (coprime with 32 banks -> free).
//   s_out: 256 rows * pitch 13 — written per-thread at pitch 13 (coprime with
//          32 banks -> free), read back as 4-float chunks for coalesced stores.

typedef float f32x4 __attribute__((ext_vector_type(4)));

template <bool EXACT>
__global__ __launch_bounds__(256) void quat_pose_kernel(
    const float* __restrict__ x, float* __restrict__ out, int B) {
    __shared__ float s_in[1792];
    __shared__ float s_out[256 * 13];

    const int t = threadIdx.x;
    const int b = blockIdx.x;

    // ---- stage 1: coalesced global -> LDS (448 x 16B per block) ----
    const long long inF4Base = 448ll * b;
    {
        const f32x4* xin4 = (const f32x4*)x;
        if (EXACT) {
            ((f32x4*)s_in)[t] = xin4[inF4Base + t];
            if (t < 192)
                ((f32x4*)s_in)[256 + t] = xin4[inF4Base + 256 + t];
        } else {
            const long long totalInF4 = (7ll * B) / 4;
            long long i0 = inF4Base + t;
            if (i0 < totalInF4) ((f32x4*)s_in)[t] = xin4[i0];
            long long i1 = inF4Base + 256 + t;
            if (t < 192 && i1 < totalInF4) ((f32x4*)s_in)[256 + t] = xin4[i1];
        }
    }
    __syncthreads();

    // ---- stage 2: compute one row per thread ----
    {
        const long long r = 256ll * b + t;
        if (EXACT || r < (long long)B) {
            const float* p = s_in + 7 * t;
            float q0 = p[0], q1 = p[1], q2 = p[2], q3 = p[3];
            float t0 = p[4], t1 = p[5], t2 = p[6];
            float q00 = q0 * q0, q11 = q1 * q1, q22 = q2 * q2, q33 = q3 * q3;
            float* w = s_out + 13 * t;
            w[0]  = q00 + q11 - q22 - q33;
            w[1]  = 2.0f * (q1 * q2 - q0 * q3);
            w[2]  = 2.0f * (q1 * q3 + q0 * q2);
            w[3]  = t0;
            w[4]  = 2.0f * (q1 * q2 + q0 * q3);
            w[5]  = q00 - q11 + q22 - q33;
            w[6]  = 2.0f * (q2 * q3 - q0 * q1);
            w[7]  = t1;
            w[8]  = 2.0f * (q1 * q3 - q0 * q2);
            w[9]  = 2.0f * (q2 * q3 + q0 * q1);
            w[10] = q00 - q11 - q22 + q33;
            w[11] = t2;
        }
    }
    __syncthreads();

    // ---- stage 3: LDS -> coalesced global (768 x 16B per block) ----
    {
        const long long outF4Base = 768ll * b;
        f32x4* out4 = (f32x4*)out;
#pragma unroll
        for (int k = 0; k < 3; k++) {
            int m = t + 256 * k;                   // local 16B index, 0..767
            long long gm = outF4Base + m;
            int row = m / 3;
            int off = 4 * (m % 3);
            f32x4 v;
            v.x = s_out[13 * row + off + 0];
            v.y = s_out[13 * row + off + 1];
            v.z = s_out[13 * row + off + 2];
            v.w = s_out[13 * row + off + 3];
            if (EXACT) {
                __builtin_nontemporal_store(v, &out4[gm]);
            } else {
                if (gm < 3ll * B) out4[gm] = v;
            }
        }
    }
}

extern "C" void kernel_launch(void* const* d_in, const int* in_sizes, int n_in,
                              void* d_out, int out_size, void* d_ws, size_t ws_size,
                              hipStream_t stream) {
    const float* x = (const float*)d_in[0];
    float* out = (float*)d_out;
    int B = in_sizes[0] / 7;                       // 4,000,000
    int grid = (B + 255) / 256;
    if (B % 256 == 0) {
        quat_pose_kernel<true><<<grid, 256, 0, stream>>>(x, out, B);
    } else {
        quat_pose_kernel<false><<<grid, 256, 0, stream>>>(x, out, B);
    }
}

// Round 2
// 257.096 us; speedup vs baseline: 1.0407x; 1.0407x over previous
//
#include <hip/hip_runtime.h>

// B = 4,000,000 rows. One row per thread, 256 rows per block.
// Stage global<->LDS so every global memory instruction is unit-stride 16B.
// Nontemporal hints on BOTH global streams (read-once input, write-once
// output): the harness's 768 MB poison fill sweeps the 256 MB L3 every
// iteration, so the input can never stay L3-resident — cacheable loads buy
// nothing and cost allocate churn (measured: removing nt = +10 us, R1).
//
// LDS layout:
//   s_in : 1792 floats (256 rows * 7), linear — written by coalesced 16B
//          loads, read per-thread at stride 7 (coprime with 32 banks -> free).
//   s_out: 256 rows * pitch 13 — written per-thread at pitch 13 (coprime with
//          32 banks -> free), read back as 4-float chunks for coalesced stores.

typedef float f32x4 __attribute__((ext_vector_type(4)));

template <bool EXACT>
__global__ __launch_bounds__(256) void quat_pose_kernel(
    const float* __restrict__ x, float* __restrict__ out, int B) {
    __shared__ float s_in[1792];
    __shared__ float s_out[256 * 13];

    const int t = threadIdx.x;
    const int b = blockIdx.x;

    // ---- stage 1: coalesced global -> LDS (448 x 16B per block) ----
    const long long inF4Base = 448ll * b;
    {
        const f32x4* xin4 = (const f32x4*)x;
        if (EXACT) {
            ((f32x4*)s_in)[t] = __builtin_nontemporal_load(&xin4[inF4Base + t]);
            if (t < 192)
                ((f32x4*)s_in)[256 + t] =
                    __builtin_nontemporal_load(&xin4[inF4Base + 256 + t]);
        } else {
            const long long totalInF4 = (7ll * B) / 4;
            long long i0 = inF4Base + t;
            if (i0 < totalInF4) ((f32x4*)s_in)[t] = xin4[i0];
            long long i1 = inF4Base + 256 + t;
            if (t < 192 && i1 < totalInF4) ((f32x4*)s_in)[256 + t] = xin4[i1];
        }
    }
    __syncthreads();

    // ---- stage 2: compute one row per thread ----
    {
        const long long r = 256ll * b + t;
        if (EXACT || r < (long long)B) {
            const float* p = s_in + 7 * t;
            float q0 = p[0], q1 = p[1], q2 = p[2], q3 = p[3];
            float t0 = p[4], t1 = p[5], t2 = p[6];
            float q00 = q0 * q0, q11 = q1 * q1, q22 = q2 * q2, q33 = q3 * q3;
            float* w = s_out + 13 * t;
            w[0]  = q00 + q11 - q22 - q33;
            w[1]  = 2.0f * (q1 * q2 - q0 * q3);
            w[2]  = 2.0f * (q1 * q3 + q0 * q2);
            w[3]  = t0;
            w[4]  = 2.0f * (q1 * q2 + q0 * q3);
            w[5]  = q00 - q11 + q22 - q33;
            w[6]  = 2.0f * (q2 * q3 - q0 * q1);
            w[7]  = t1;
            w[8]  = 2.0f * (q1 * q3 - q0 * q2);
            w[9]  = 2.0f * (q2 * q3 + q0 * q1);
            w[10] = q00 - q11 - q22 + q33;
            w[11] = t2;
        }
    }
    __syncthreads();

    // ---- stage 3: LDS -> coalesced global (768 x 16B per block) ----
    {
        const long long outF4Base = 768ll * b;
        f32x4* out4 = (f32x4*)out;
#pragma unroll
        for (int k = 0; k < 3; k++) {
            int m = t + 256 * k;                   // local 16B index, 0..767
            long long gm = outF4Base + m;
            int row = m / 3;
            int off = 4 * (m % 3);
            f32x4 v;
            v.x = s_out[13 * row + off + 0];
            v.y = s_out[13 * row + off + 1];
            v.z = s_out[13 * row + off + 2];
            v.w = s_out[13 * row + off + 3];
            if (EXACT) {
                __builtin_nontemporal_store(v, &out4[gm]);
            } else {
                if (gm < 3ll * B) out4[gm] = v;
            }
        }
    }
}

extern "C" void kernel_launch(void* const* d_in, const int* in_sizes, int n_in,
                              void* d_out, int out_size, void* d_ws, size_t ws_size,
                              hipStream_t stream) {
    const float* x = (const float*)d_in[0];
    float* out = (float*)d_out;
    int B = in_sizes[0] / 7;                       // 4,000,000
    int grid = (B + 255) / 256;
    if (B % 256 == 0) {
        quat_pose_kernel<true><<<grid, 256, 0, stream>>>(x, out, B);
    } else {
        quat_pose_kernel<false><<<grid, 256, 0, stream>>>(x, out, B);
    }
}